// Round 1
// baseline (219.905 us; speedup 1.0000x reference)
//
#include <hip/hip_runtime.h>
#include <hip/hip_bf16.h>
#include <math.h>

// Problem constants (fixed by reference setup_inputs)
#define B_   4
#define D_   64
#define HW_  4096
#define N_   16384
#define M_   4096

#define MTILE  128          // codes per block
#define NSPLIT 16           // n-splits across grid
#define NCHUNK (N_ / NSPLIT)   // 1024 rows per block
#define NTILES (NCHUNK / 64)   // 16 z-tiles of 64 rows

// ws layout in floats
#define ZN_OFF   0          // z_norm[16384]
#define EN_OFF   16384      // e_norm[4096]
#define PART_OFF 20480      // partial[NSPLIT][4096]

__global__ void norms_kernel(const float* __restrict__ z,
                             const float* __restrict__ e,
                             float* __restrict__ ws) {
    int blk = blockIdx.x;
    int t = threadIdx.x;
    if (blk < 64) {
        // z_norm: n = b*HW + hw ; z[b][d][hw]
        int n = blk * 256 + t;
        int b = n >> 12;
        int hw = n & 4095;
        const float* zp = z + (size_t)b * D_ * HW_ + hw;
        float s = 0.f;
#pragma unroll
        for (int d = 0; d < D_; ++d) { float v = zp[(size_t)d * HW_]; s += v * v; }
        ws[ZN_OFF + n] = s;
    } else {
        int m = (blk - 64) * 256 + t;
        const float4* ep = (const float4*)(e + (size_t)m * D_);
        float s = 0.f;
#pragma unroll
        for (int k = 0; k < 16; ++k) {
            float4 v = ep[k];
            s += v.x * v.x + v.y * v.y + v.z * v.z + v.w * v.w;
        }
        ws[EN_OFF + m] = s;
    }
}

__global__ __launch_bounds__(256) void main_kernel(
        const float* __restrict__ z, const float* __restrict__ e,
        const float* __restrict__ lsp, const float* __restrict__ ws_r,
        float* __restrict__ partial) {
    __shared__ float lds_z[64][68];          // [d][n_local], padded
    __shared__ float lds_e[64][MTILE + 4];   // [d][m_local], stride 132
    __shared__ float lds_red[MTILE];

    const int mt = blockIdx.x;   // 0..31
    const int ns = blockIdx.y;   // 0..15
    const int m0 = mt * MTILE;
    const int t  = threadIdx.x;
    const int tx = t & 15;       // m-octet: m_local = tx*8 + j
    const int ty = t >> 4;       // n-quad : n_local = ty*4 + i

    const float ls = lsp[0];
    const float alpha = -0.5f * __expf(-2.f * ls);   // -1/(2*exp(ls)^2), T=1

    // stage e tile: [d][m] layout (coalesced global read along d)
    for (int k = t; k < MTILE * 64; k += 256) {
        int m = k >> 6, d = k & 63;
        lds_e[d][m] = e[(size_t)(m0 + m) * D_ + d];
    }

    const float* z_norm = ws_r + ZN_OFF;
    const float* e_norm = ws_r + EN_OFF;
    float en[8];
#pragma unroll
    for (int j = 0; j < 8; ++j) en[j] = e_norm[m0 + tx * 8 + j];

    float sum_loc[8] = {0.f, 0.f, 0.f, 0.f, 0.f, 0.f, 0.f, 0.f};

    for (int tb = 0; tb < NTILES; ++tb) {
        int n0 = ns * NCHUNK + tb * 64;
        int b   = n0 >> 12;      // 64-row tile never crosses b boundary
        int hw0 = n0 & 4095;
        __syncthreads();   // protect lds_z reuse (also covers initial lds_e fill)
        for (int k = t; k < 64 * 64; k += 256) {
            int dd = k >> 6, hw = k & 63;
            lds_z[dd][hw] = z[((size_t)b * D_ + dd) * HW_ + hw0 + hw];
        }
        __syncthreads();

        float acc[4][8];
#pragma unroll
        for (int i = 0; i < 4; ++i)
#pragma unroll
            for (int j = 0; j < 8; ++j) acc[i][j] = 0.f;

#pragma unroll 8
        for (int d = 0; d < 64; ++d) {
            float4 zv  = *(const float4*)&lds_z[d][ty * 4];
            float4 ev0 = *(const float4*)&lds_e[d][tx * 8];
            float4 ev1 = *(const float4*)&lds_e[d][tx * 8 + 4];
            float zz[4] = {zv.x, zv.y, zv.z, zv.w};
            float ee[8] = {ev0.x, ev0.y, ev0.z, ev0.w, ev1.x, ev1.y, ev1.z, ev1.w};
#pragma unroll
            for (int i = 0; i < 4; ++i)
#pragma unroll
                for (int j = 0; j < 8; ++j)
                    acc[i][j] = fmaf(zz[i], ee[j], acc[i][j]);
        }

        // fused exp-accumulate epilogue (no max needed: entries <= 0, col max ~ -35)
#pragma unroll
        for (int i = 0; i < 4; ++i) {
            float zn = z_norm[n0 + ty * 4 + i];
#pragma unroll
            for (int j = 0; j < 8; ++j) {
                sum_loc[j] += __expf(alpha * (zn + en[j] - 2.f * acc[i][j]));
            }
        }
    }

    // reduce partial column sums across the 16 ty-groups
    for (int k = t; k < MTILE; k += 256) lds_red[k] = 0.f;
    __syncthreads();
#pragma unroll
    for (int j = 0; j < 8; ++j) atomicAdd(&lds_red[tx * 8 + j], sum_loc[j]);
    __syncthreads();
    for (int k = t; k < MTILE; k += 256)
        partial[(size_t)ns * M_ + m0 + k] = lds_red[k];
}

__global__ void finalize_kernel(const float* __restrict__ partial,
                                const float* __restrict__ lsp,
                                float* __restrict__ out) {
    __shared__ double red[256];
    int t = threadIdx.x;
    double local = 0.0;
    for (int m = t; m < M_; m += 256) {
        float s = 0.f;
#pragma unroll
        for (int k = 0; k < NSPLIT; ++k) s += partial[(size_t)k * M_ + m];
        local += (double)logf(s);
    }
    red[t] = local;
    __syncthreads();
    for (int off = 128; off > 0; off >>= 1) {
        if (t < off) red[t] += red[t + off];
        __syncthreads();
    }
    if (t == 0) {
        double ls = (double)lsp[0];
        double loss = -(red[0] / (double)M_)
                      + 0.5 * (double)D_ * (2.0 * ls - 1.0)
                      + log((double)N_);
        out[0] = (float)loss;
    }
}

extern "C" void kernel_launch(void* const* d_in, const int* in_sizes, int n_in,
                              void* d_out, int out_size, void* d_ws, size_t ws_size,
                              hipStream_t stream) {
    const float* z   = (const float*)d_in[0];
    const float* e   = (const float*)d_in[1];
    const float* lsp = (const float*)d_in[2];
    float* ws  = (float*)d_ws;
    float* out = (float*)d_out;

    hipLaunchKernelGGL(norms_kernel, dim3(80), dim3(256), 0, stream, z, e, ws);
    hipLaunchKernelGGL(main_kernel, dim3(32, NSPLIT), dim3(256), 0, stream,
                       z, e, lsp, ws, ws + PART_OFF);
    hipLaunchKernelGGL(finalize_kernel, dim3(1), dim3(256), 0, stream,
                       ws + PART_OFF, lsp, out);
}

// Round 2
// 127.115 us; speedup vs baseline: 1.7300x; 1.7300x over previous
//
#include <hip/hip_runtime.h>
#include <hip/hip_bf16.h>
#include <math.h>

// Problem constants (fixed by reference setup_inputs)
#define D_   64
#define HW_  4096
#define N_   16384
#define M_   4096

#define BM 128                 // codes per block
#define BN 128                 // z-rows per A-tile stage
#define NSPLIT 32              // n-splits across grid
#define NCHUNK (N_ / NSPLIT)   // 512 rows per block
#define NTILES (NCHUNK / BN)   // 4 A-tiles per block

// ws layout in floats
#define AZN_OFF  0             // alpha*||z_n||^2  [16384]
#define AEN_OFF  N_            // alpha*||e_m||^2  [4096]
#define PART_OFF (N_ + M_)     // partial[NSPLIT][4096]

typedef __attribute__((ext_vector_type(8))) short short8;
typedef __attribute__((ext_vector_type(16))) float floatx16;

__device__ __forceinline__ unsigned int bf16_rne(float x) {
    unsigned int u = __float_as_uint(x);
    u += 0x7fffu + ((u >> 16) & 1u);
    return u >> 16;
}

__global__ void norms_kernel(const float* __restrict__ z,
                             const float* __restrict__ e,
                             const float* __restrict__ lsp,
                             float* __restrict__ ws) {
    float ls = lsp[0];
    float alpha = -0.5f * __expf(-2.f * ls);   // -1/(2*exp(ls)^2), T=1
    int blk = blockIdx.x, t = threadIdx.x;
    if (blk < 64) {
        int n = blk * 256 + t;
        int b = n >> 12, hw = n & 4095;
        const float* zp = z + (size_t)b * D_ * HW_ + hw;
        float s = 0.f;
#pragma unroll
        for (int d = 0; d < D_; ++d) { float v = zp[(size_t)d * HW_]; s = fmaf(v, v, s); }
        ws[AZN_OFF + n] = alpha * s;
    } else {
        int m = (blk - 64) * 256 + t;
        const float4* ep = (const float4*)(e + (size_t)m * D_);
        float s = 0.f;
#pragma unroll
        for (int k = 0; k < 16; ++k) {
            float4 v = ep[k];
            s += v.x * v.x + v.y * v.y + v.z * v.z + v.w * v.w;
        }
        ws[AEN_OFF + m] = alpha * s;
    }
}

// LDS tile layout: element (row, d) lives at ushort index
//   unit(row, d>>3) * 8 + (d & 7),  unit(row,g) = row*8 + (g ^ (row & 7))
// -> b128 fragment reads (8 consecutive d for row=lane&31) are swizzle-spread
//    across bank groups (canonical conflict-free pattern), no padding, 16B aligned.
__global__ __launch_bounds__(256, 2) void main_kernel(
        const float* __restrict__ z, const float* __restrict__ e,
        const float* __restrict__ lsp, const float* __restrict__ ws,
        float* __restrict__ partial) {
    __shared__ unsigned short lds_a[BN * 64];   // 16 KB
    __shared__ unsigned short lds_b[BM * 64];   // 16 KB
    __shared__ float lds_azn[BN];
    __shared__ float lds_red[BM];

    const int mblk = blockIdx.x;    // 0..31
    const int ns   = blockIdx.y;    // 0..31
    const int m0   = mblk * BM;
    const int t    = threadIdx.x;
    const int lane = t & 63;
    const int w    = t >> 6;        // wave id: n-subtile within A-tile
    const int rlo  = lane & 31;     // MFMA row/col lane index
    const int kh   = lane >> 5;     // k-half select

    const float ls = lsp[0];
    const float c2 = __expf(-2.f * ls);   // = -2*alpha  (>0)

    const float* azn_g = ws + AZN_OFF;
    const float* aen_g = ws + AEN_OFF;

    // ---- stage B tile (e -> bf16, swizzled [m][d]) once ----
#pragma unroll
    for (int i = 0; i < 8; ++i) {
        int idx = t + 256 * i;
        int m = idx >> 4, f4 = idx & 15;          // d = f4*4 .. +3
        float4 v = *(const float4*)(e + (size_t)(m0 + m) * D_ + f4 * 4);
        unsigned int p0 = bf16_rne(v.x) | (bf16_rne(v.y) << 16);
        unsigned int p1 = bf16_rne(v.z) | (bf16_rne(v.w) << 16);
        int un = m * 8 + ((f4 >> 1) ^ (m & 7));
        unsigned int* dst = (unsigned int*)&lds_b[un * 8 + (f4 & 1) * 4];
        dst[0] = p0; dst[1] = p1;
    }
    float aen_r[4];
#pragma unroll
    for (int mt = 0; mt < 4; ++mt) aen_r[mt] = aen_g[m0 + mt * 32 + rlo];
    __syncthreads();

    // ---- B fragments live in registers for the whole kernel (64 VGPR) ----
    short8 bf[4][4];
#pragma unroll
    for (int mt = 0; mt < 4; ++mt)
#pragma unroll
        for (int ks = 0; ks < 4; ++ks) {
            int row = mt * 32 + rlo;
            int g = ks * 2 + kh;
            bf[mt][ks] = *(const short8*)&lds_b[(row * 8 + (g ^ (row & 7))) * 8];
        }

    float sum[4] = {0.f, 0.f, 0.f, 0.f};

    for (int tile = 0; tile < NTILES; ++tile) {
        int n0  = ns * NCHUNK + tile * BN;
        int b   = n0 >> 12;                // 128-row tile never crosses b
        int hw0 = n0 & 4095;
        __syncthreads();
        // stage A tile: transpose z[d][hw] -> lds_a[n][d] bf16, packed d-pairs
#pragma unroll
        for (int i = 0; i < 4; ++i) {
            int idx = t + 256 * i;
            int dp = idx >> 5;             // d = 2dp, 2dp+1
            int c4 = idx & 31;             // rows c4*4 .. +3
            int d0 = dp * 2;
            const float* zp = z + ((size_t)(b * D_ + d0)) * HW_ + hw0 + c4 * 4;
            float4 v0 = *(const float4*)zp;
            float4 v1 = *(const float4*)(zp + HW_);
            int g = d0 >> 3;
            float a0[4] = {v0.x, v0.y, v0.z, v0.w};
            float a1[4] = {v1.x, v1.y, v1.z, v1.w};
#pragma unroll
            for (int q = 0; q < 4; ++q) {
                int row = c4 * 4 + q;
                unsigned int pk = bf16_rne(a0[q]) | (bf16_rne(a1[q]) << 16);
                int un = row * 8 + (g ^ (row & 7));
                *(unsigned int*)&lds_a[un * 8 + (d0 & 7)] = pk;
            }
        }
        if (t < BN) lds_azn[t] = azn_g[n0 + t];
        __syncthreads();

        // A fragments for this wave's 32-row subtile
        short8 af[4];
        int arow = w * 32 + rlo;
#pragma unroll
        for (int ks = 0; ks < 4; ++ks) {
            int g = ks * 2 + kh;
            af[ks] = *(const short8*)&lds_a[(arow * 8 + (g ^ (arow & 7))) * 8];
        }
        // azn for this lane's 16 C-rows: row = (r&3) + 8*(r>>2) + 4*kh
        float azn_r[16];
        int r0 = w * 32 + 4 * kh;
#pragma unroll
        for (int rg = 0; rg < 4; ++rg) {
            float4 vv = *(const float4*)&lds_azn[r0 + 8 * rg];
            azn_r[rg * 4 + 0] = vv.x; azn_r[rg * 4 + 1] = vv.y;
            azn_r[rg * 4 + 2] = vv.z; azn_r[rg * 4 + 3] = vv.w;
        }

        floatx16 acc[4] = {};
#pragma unroll
        for (int ks = 0; ks < 4; ++ks)
#pragma unroll
            for (int mt = 0; mt < 4; ++mt)
                acc[mt] = __builtin_amdgcn_mfma_f32_32x32x16_bf16(
                    af[ks], bf[mt][ks], acc[mt], 0, 0, 0);

        // fused epilogue: val = alpha*(zn + en - 2*dot); sum_m += exp(val)
#pragma unroll
        for (int mt = 0; mt < 4; ++mt) {
            float s = 0.f;
#pragma unroll
            for (int r = 0; r < 16; ++r) {
                float val = fmaf(acc[mt][r], c2, azn_r[r]) + aen_r[mt];
                s += __expf(val);
            }
            sum[mt] += s;
        }
    }

    // lane l and l+32 hold the same column -> fold halves
#pragma unroll
    for (int mt = 0; mt < 4; ++mt) sum[mt] += __shfl_down(sum[mt], 32);

    __syncthreads();
    if (t < BM) lds_red[t] = 0.f;
    __syncthreads();
    if (rlo == (lane & 31) && lane < 32) {
#pragma unroll
        for (int mt = 0; mt < 4; ++mt) atomicAdd(&lds_red[mt * 32 + rlo], sum[mt]);
    }
    __syncthreads();
    if (t < BM) partial[(size_t)ns * M_ + m0 + t] = lds_red[t];
}

__global__ void finalize_kernel(const float* __restrict__ partial,
                                const float* __restrict__ lsp,
                                float* __restrict__ out) {
    __shared__ double red[256];
    int t = threadIdx.x;
    double local = 0.0;
    for (int j = 0; j < 16; ++j) {
        int m = t + 256 * j;
        float s = 0.f;
#pragma unroll
        for (int k = 0; k < NSPLIT; ++k) s += partial[(size_t)k * M_ + m];
        local += (double)logf(s);
    }
    red[t] = local;
    __syncthreads();
    for (int off = 128; off > 0; off >>= 1) {
        if (t < off) red[t] += red[t + off];
        __syncthreads();
    }
    if (t == 0) {
        double ls = (double)lsp[0];
        double loss = -(red[0] / (double)M_)
                      + 0.5 * (double)D_ * (2.0 * ls - 1.0)
                      + log((double)N_);
        out[0] = (float)loss;
    }
}

extern "C" void kernel_launch(void* const* d_in, const int* in_sizes, int n_in,
                              void* d_out, int out_size, void* d_ws, size_t ws_size,
                              hipStream_t stream) {
    const float* z   = (const float*)d_in[0];
    const float* e   = (const float*)d_in[1];
    const float* lsp = (const float*)d_in[2];
    float* ws  = (float*)d_ws;
    float* out = (float*)d_out;

    hipLaunchKernelGGL(norms_kernel, dim3(80), dim3(256), 0, stream, z, e, lsp, ws);
    hipLaunchKernelGGL(main_kernel, dim3(M_ / BM, NSPLIT), dim3(256), 0, stream,
                       z, e, lsp, ws, ws + PART_OFF);
    hipLaunchKernelGGL(finalize_kernel, dim3(1), dim3(256), 0, stream,
                       ws + PART_OFF, lsp, out);
}

// Round 4
// 86.467 us; speedup vs baseline: 2.5432x; 1.4701x over previous
//
#include <hip/hip_runtime.h>
#include <hip/hip_bf16.h>
#include <math.h>

#define D_   64
#define HW_  4096
#define N_   16384
#define M_   4096

#define BM 128                 // codes per block
#define NSPLIT 32              // n-splits across grid
#define NCHUNK (N_ / NSPLIT)   // 512 rows per block
#define NTILES (NCHUNK / 128)  // 4 tiles of 128 rows (4 waves x 32)

// ---- fast-path ws layout (floats) ----
#define AZN_OFF 0                      // azn'[16384]
#define AEN_OFF 16384                  // aen'[4096]
#define SUM_OFF 20480                  // sums[4096]
#define ZTB_OFF 24576                  // zT bf16 [16384][64] = 524288 floats
#define EBF_OFF (24576 + 524288)       // e  bf16 [4096][64]  = 131072 floats
#define FAST_WS_FLOATS (EBF_OFF + 131072)

// ---- fallback ws layout (floats) ----
#define FB_AZN 0
#define FB_AEN N_
#define FB_PART (N_ + M_)              // partial[NSPLIT][4096]

#define L2E 1.4426950408889634f

typedef __attribute__((ext_vector_type(8))) short short8;
typedef __attribute__((ext_vector_type(16))) float floatx16;

#if __has_builtin(__builtin_amdgcn_exp2f)
#define EXP2F(x) __builtin_amdgcn_exp2f(x)
#else
#define EXP2F(x) exp2f(x)
#endif

__device__ __forceinline__ unsigned int bf16_rne(float x) {
    unsigned int u = __float_as_uint(x);
    u += 0x7fffu + ((u >> 16) & 1u);
    return u >> 16;
}

// ======================= FAST PATH =======================

// blocks 0..255: z transpose+scale+norm ; blocks 256..271: e convert+norm+zero sums
__global__ void prep_kernel(const float* __restrict__ z,
                            const float* __restrict__ e,
                            const float* __restrict__ lsp,
                            float* __restrict__ ws) {
    const float ls = lsp[0];
    const float alpha = -0.5f * __expf(-2.f * ls);   // -1/(2 e^{2ls})
    const float anl = alpha * L2E;                   // norm scale (log2 domain)
    const float c2p = -2.f * alpha * L2E;            // z pre-scale
    unsigned short* zTb = (unsigned short*)(ws + ZTB_OFF);
    unsigned short* ebf = (unsigned short*)(ws + EBF_OFF);
    const int blk = blockIdx.x, t = threadIdx.x;

    if (blk < 256) {
        __shared__ float lt[64 * 65];
        const int b = blk >> 6, hw0 = (blk & 63) * 64;
        const int n0 = b * HW_ + hw0;
        const float* zb = z + ((size_t)b * D_) * HW_ + hw0;
#pragma unroll
        for (int i = 0; i < 4; ++i) {
            int idx = t + 256 * i;
            int d = idx >> 4, c = (idx & 15) * 4;
            float4 v = *(const float4*)(zb + (size_t)d * HW_ + c);
            float* p = &lt[d * 65 + c];
            p[0] = v.x; p[1] = v.y; p[2] = v.z; p[3] = v.w;
        }
        __syncthreads();
#pragma unroll
        for (int j = 0; j < 2; ++j) {
            int idx = t + 256 * j;
            int nl = idx >> 3, g = idx & 7;
            float v[8]; float s = 0.f;
#pragma unroll
            for (int jj = 0; jj < 8; ++jj) {
                v[jj] = lt[(8 * g + jj) * 65 + nl];
                s = fmaf(v[jj], v[jj], s);
            }
            s += __shfl_xor(s, 1);
            s += __shfl_xor(s, 2);
            s += __shfl_xor(s, 4);
            uint4 pk;
            pk.x = bf16_rne(v[0] * c2p) | (bf16_rne(v[1] * c2p) << 16);
            pk.y = bf16_rne(v[2] * c2p) | (bf16_rne(v[3] * c2p) << 16);
            pk.z = bf16_rne(v[4] * c2p) | (bf16_rne(v[5] * c2p) << 16);
            pk.w = bf16_rne(v[6] * c2p) | (bf16_rne(v[7] * c2p) << 16);
            *(uint4*)(zTb + (size_t)(n0 + nl) * 64 + 8 * g) = pk;
            if (g == 0) ws[AZN_OFF + n0 + nl] = anl * s;
        }
    } else {
        int m = (blk - 256) * 256 + t;
        const float4* ep = (const float4*)(e + (size_t)m * D_);
        float s = 0.f;
        unsigned int pk[32];
#pragma unroll
        for (int k = 0; k < 16; ++k) {
            float4 v = ep[k];
            s += v.x * v.x + v.y * v.y + v.z * v.z + v.w * v.w;
            pk[2 * k]     = bf16_rne(v.x) | (bf16_rne(v.y) << 16);
            pk[2 * k + 1] = bf16_rne(v.z) | (bf16_rne(v.w) << 16);
        }
        uint4* op = (uint4*)(ebf + (size_t)m * 64);
#pragma unroll
        for (int k = 0; k < 8; ++k)
            op[k] = make_uint4(pk[4 * k], pk[4 * k + 1], pk[4 * k + 2], pk[4 * k + 3]);
        ws[AEN_OFF + m] = anl * s;
        ws[SUM_OFF + m] = 0.f;
    }
}

__global__ __launch_bounds__(256, 2) void main_fast(float* __restrict__ ws) {
    __shared__ float lds_red[BM];
    const unsigned short* zTb = (const unsigned short*)(ws + ZTB_OFF);
    const unsigned short* ebf = (const unsigned short*)(ws + EBF_OFF);
    const float* azn = ws + AZN_OFF;
    const float* aen = ws + AEN_OFF;
    float* sums = ws + SUM_OFF;

    const int m0 = blockIdx.x * BM;
    const int ns = blockIdx.y;
    const int t = threadIdx.x;
    const int lane = t & 63;
    const int w = t >> 6;
    const int rlo = lane & 31;
    const int kh = lane >> 5;

    // B fragments: e rows, register-resident for whole kernel
    short8 bf[4][4];
    float aen_r[4];
#pragma unroll
    for (int mt = 0; mt < 4; ++mt) {
        int row = m0 + mt * 32 + rlo;
        aen_r[mt] = aen[row];
#pragma unroll
        for (int ks = 0; ks < 4; ++ks)
            bf[mt][ks] = *(const short8*)(ebf + (size_t)row * 64 + (ks * 2 + kh) * 8);
    }

    float sum[4] = {0.f, 0.f, 0.f, 0.f};
    const int nbase = ns * NCHUNK + w * 32;

#pragma unroll
    for (int tile = 0; tile < NTILES; ++tile) {
        const int nr = nbase + tile * 128;
        short8 af[4];
#pragma unroll
        for (int ks = 0; ks < 4; ++ks)
            af[ks] = *(const short8*)(zTb + (size_t)(nr + rlo) * 64 + (ks * 2 + kh) * 8);

        float azn_r[16];
        const int r0 = nr + 4 * kh;
#pragma unroll
        for (int rg = 0; rg < 4; ++rg) {
            float4 vv = *(const float4*)(azn + r0 + 8 * rg);
            azn_r[rg * 4 + 0] = vv.x; azn_r[rg * 4 + 1] = vv.y;
            azn_r[rg * 4 + 2] = vv.z; azn_r[rg * 4 + 3] = vv.w;
        }

        floatx16 acc[4];
#pragma unroll
        for (int mt = 0; mt < 4; ++mt)
#pragma unroll
            for (int r = 0; r < 16; ++r)
                acc[mt][r] = azn_r[r] + aen_r[mt];

#pragma unroll
        for (int ks = 0; ks < 4; ++ks)
#pragma unroll
            for (int mt = 0; mt < 4; ++mt)
                acc[mt] = __builtin_amdgcn_mfma_f32_32x32x16_bf16(
                    af[ks], bf[mt][ks], acc[mt], 0, 0, 0);

        // epilogue: acc already holds log2-domain exponent -> exp2 + accumulate
#pragma unroll
        for (int mt = 0; mt < 4; ++mt) {
            float s = 0.f;
#pragma unroll
            for (int r = 0; r < 16; ++r) s += EXP2F(acc[mt][r]);
            sum[mt] += s;
        }
    }

#pragma unroll
    for (int mt = 0; mt < 4; ++mt) sum[mt] += __shfl_down(sum[mt], 32);

    if (t < BM) lds_red[t] = 0.f;
    __syncthreads();
    if (lane < 32) {
#pragma unroll
        for (int mt = 0; mt < 4; ++mt) atomicAdd(&lds_red[mt * 32 + rlo], sum[mt]);
    }
    __syncthreads();
    if (t < BM) atomicAdd(&sums[m0 + t], lds_red[t]);
}

__global__ void finalize_fast(const float* __restrict__ ws,
                              const float* __restrict__ lsp,
                              float* __restrict__ out) {
    __shared__ double red[256];
    const float* sums = ws + SUM_OFF;
    int t = threadIdx.x;
    double local = 0.0;
#pragma unroll
    for (int j = 0; j < 16; ++j) {
        float s = sums[t + 256 * j];
        local += (double)logf(s);
    }
    red[t] = local;
    __syncthreads();
    for (int off = 128; off > 0; off >>= 1) {
        if (t < off) red[t] += red[t + off];
        __syncthreads();
    }
    if (t == 0) {
        double ls = (double)lsp[0];
        double loss = -(red[0] / (double)M_)
                      + 0.5 * (double)D_ * (2.0 * ls - 1.0)
                      + log((double)N_);
        out[0] = (float)loss;
    }
}

// ======================= FALLBACK (R2, proven) =======================

__global__ void norms_kernel(const float* __restrict__ z,
                             const float* __restrict__ e,
                             const float* __restrict__ lsp,
                             float* __restrict__ ws) {
    float ls = lsp[0];
    float alpha = -0.5f * __expf(-2.f * ls);
    int blk = blockIdx.x, t = threadIdx.x;
    if (blk < 64) {
        int n = blk * 256 + t;
        int b = n >> 12, hw = n & 4095;
        const float* zp = z + (size_t)b * D_ * HW_ + hw;
        float s = 0.f;
#pragma unroll
        for (int d = 0; d < D_; ++d) { float v = zp[(size_t)d * HW_]; s = fmaf(v, v, s); }
        ws[FB_AZN + n] = alpha * s;
    } else {
        int m = (blk - 64) * 256 + t;
        const float4* ep = (const float4*)(e + (size_t)m * D_);
        float s = 0.f;
#pragma unroll
        for (int k = 0; k < 16; ++k) {
            float4 v = ep[k];
            s += v.x * v.x + v.y * v.y + v.z * v.z + v.w * v.w;
        }
        ws[FB_AEN + m] = alpha * s;
    }
}

__global__ __launch_bounds__(256, 2) void main_lds(
        const float* __restrict__ z, const float* __restrict__ e,
        const float* __restrict__ lsp, const float* __restrict__ ws,
        float* __restrict__ partial) {
    __shared__ unsigned short lds_a[128 * 64];
    __shared__ unsigned short lds_b[BM * 64];
    __shared__ float lds_azn[128];
    __shared__ float lds_red[BM];

    const int m0 = blockIdx.x * BM;
    const int ns = blockIdx.y;
    const int t = threadIdx.x;
    const int lane = t & 63;
    const int w = t >> 6;
    const int rlo = lane & 31;
    const int kh = lane >> 5;

    const float ls = lsp[0];
    const float c2 = __expf(-2.f * ls);

    const float* azn_g = ws + FB_AZN;
    const float* aen_g = ws + FB_AEN;

#pragma unroll
    for (int i = 0; i < 8; ++i) {
        int idx = t + 256 * i;
        int m = idx >> 4, f4 = idx & 15;
        float4 v = *(const float4*)(e + (size_t)(m0 + m) * D_ + f4 * 4);
        unsigned int p0 = bf16_rne(v.x) | (bf16_rne(v.y) << 16);
        unsigned int p1 = bf16_rne(v.z) | (bf16_rne(v.w) << 16);
        int un = m * 8 + ((f4 >> 1) ^ (m & 7));
        unsigned int* dst = (unsigned int*)&lds_b[un * 8 + (f4 & 1) * 4];
        dst[0] = p0; dst[1] = p1;
    }
    float aen_r[4];
#pragma unroll
    for (int mt = 0; mt < 4; ++mt) aen_r[mt] = aen_g[m0 + mt * 32 + rlo];
    __syncthreads();

    short8 bfr[4][4];
#pragma unroll
    for (int mt = 0; mt < 4; ++mt)
#pragma unroll
        for (int ks = 0; ks < 4; ++ks) {
            int row = mt * 32 + rlo;
            int g = ks * 2 + kh;
            bfr[mt][ks] = *(const short8*)&lds_b[(row * 8 + (g ^ (row & 7))) * 8];
        }

    float sum[4] = {0.f, 0.f, 0.f, 0.f};

    for (int tile = 0; tile < NTILES; ++tile) {
        int n0 = ns * NCHUNK + tile * 128;
        int b   = n0 >> 12;
        int hw0 = n0 & 4095;
        __syncthreads();
#pragma unroll
        for (int i = 0; i < 4; ++i) {
            int idx = t + 256 * i;
            int dp = idx >> 5;
            int c4 = idx & 31;
            int d0 = dp * 2;
            const float* zp = z + ((size_t)(b * D_ + d0)) * HW_ + hw0 + c4 * 4;
            float4 v0 = *(const float4*)zp;
            float4 v1 = *(const float4*)(zp + HW_);
            int g = d0 >> 3;
            float a0[4] = {v0.x, v0.y, v0.z, v0.w};
            float a1[4] = {v1.x, v1.y, v1.z, v1.w};
#pragma unroll
            for (int q = 0; q < 4; ++q) {
                int row = c4 * 4 + q;
                unsigned int pk = bf16_rne(a0[q]) | (bf16_rne(a1[q]) << 16);
                int un = row * 8 + (g ^ (row & 7));
                *(unsigned int*)&lds_a[un * 8 + (d0 & 7)] = pk;
            }
        }
        if (t < 128) lds_azn[t] = azn_g[n0 + t];
        __syncthreads();

        short8 af[4];
        int arow = w * 32 + rlo;
#pragma unroll
        for (int ks = 0; ks < 4; ++ks) {
            int g = ks * 2 + kh;
            af[ks] = *(const short8*)&lds_a[(arow * 8 + (g ^ (arow & 7))) * 8];
        }
        float azn_r[16];
        int r0 = w * 32 + 4 * kh;
#pragma unroll
        for (int rg = 0; rg < 4; ++rg) {
            float4 vv = *(const float4*)&lds_azn[r0 + 8 * rg];
            azn_r[rg * 4 + 0] = vv.x; azn_r[rg * 4 + 1] = vv.y;
            azn_r[rg * 4 + 2] = vv.z; azn_r[rg * 4 + 3] = vv.w;
        }

        floatx16 acc[4] = {};
#pragma unroll
        for (int ks = 0; ks < 4; ++ks)
#pragma unroll
            for (int mt = 0; mt < 4; ++mt)
                acc[mt] = __builtin_amdgcn_mfma_f32_32x32x16_bf16(
                    af[ks], bfr[mt][ks], acc[mt], 0, 0, 0);

#pragma unroll
        for (int mt = 0; mt < 4; ++mt) {
            float s = 0.f;
#pragma unroll
            for (int r = 0; r < 16; ++r) {
                float val = fmaf(acc[mt][r], c2, azn_r[r]) + aen_r[mt];
                s += __expf(val);
            }
            sum[mt] += s;
        }
    }

#pragma unroll
    for (int mt = 0; mt < 4; ++mt) sum[mt] += __shfl_down(sum[mt], 32);

    __syncthreads();
    if (t < BM) lds_red[t] = 0.f;
    __syncthreads();
    if (lane < 32) {
#pragma unroll
        for (int mt = 0; mt < 4; ++mt) atomicAdd(&lds_red[mt * 32 + rlo], sum[mt]);
    }
    __syncthreads();
    if (t < BM) partial[(size_t)ns * M_ + m0 + t] = lds_red[t];
}

__global__ void finalize_part(const float* __restrict__ partial,
                              const float* __restrict__ lsp,
                              float* __restrict__ out) {
    __shared__ double red[256];
    int t = threadIdx.x;
    double local = 0.0;
#pragma unroll
    for (int j = 0; j < 16; ++j) {
        int m = t + 256 * j;
        float s = 0.f;
#pragma unroll
        for (int k = 0; k < NSPLIT; ++k) s += partial[(size_t)k * M_ + m];
        local += (double)logf(s);
    }
    red[t] = local;
    __syncthreads();
    for (int off = 128; off > 0; off >>= 1) {
        if (t < off) red[t] += red[t + off];
        __syncthreads();
    }
    if (t == 0) {
        double ls = (double)lsp[0];
        double loss = -(red[0] / (double)M_)
                      + 0.5 * (double)D_ * (2.0 * ls - 1.0)
                      + log((double)N_);
        out[0] = (float)loss;
    }
}

extern "C" void kernel_launch(void* const* d_in, const int* in_sizes, int n_in,
                              void* d_out, int out_size, void* d_ws, size_t ws_size,
                              hipStream_t stream) {
    const float* z   = (const float*)d_in[0];
    const float* e   = (const float*)d_in[1];
    const float* lsp = (const float*)d_in[2];
    float* ws  = (float*)d_ws;
    float* out = (float*)d_out;

    if (ws_size >= (size_t)FAST_WS_FLOATS * sizeof(float)) {
        hipLaunchKernelGGL(prep_kernel, dim3(272), dim3(256), 0, stream, z, e, lsp, ws);
        hipLaunchKernelGGL(main_fast, dim3(M_ / BM, NSPLIT), dim3(256), 0, stream, ws);
        hipLaunchKernelGGL(finalize_fast, dim3(1), dim3(256), 0, stream, ws, lsp, out);
    } else {
        hipLaunchKernelGGL(norms_kernel, dim3(80), dim3(256), 0, stream, z, e, lsp, ws);
        hipLaunchKernelGGL(main_lds, dim3(M_ / BM, NSPLIT), dim3(256), 0, stream,
                           z, e, lsp, ws, ws + FB_PART);
        hipLaunchKernelGGL(finalize_part, dim3(1), dim3(256), 0, stream,
                           ws + FB_PART, lsp, out);
    }
}